// Round 2
// baseline (2996.502 us; speedup 1.0000x reference)
//
#include <hip/hip_runtime.h>
#include <math.h>

// Problem constants
#define DD 512
#define NN 128
#define XBASE 385   // D - N + 1 ; xmax_k = XBASE + k

// Workspace layout (in 4-byte elements)
#define OFF_M      0            // 512*512 chain matrix
#define OFF_LP     262144       // 512*32  full L/U panel block (all rows incl L11/U11)
#define OFF_UP     278528       // (unused now)
#define OFF_CPIV   294912       // 512     chain pivots (unshadowed diag at elimination time)
#define OFF_SHAD   295424       // 128     running shadow diagonals
#define OFF_SSNAP  295552       // 16*128  shadow snapshot at start of each stage
#define OFF_FPIV   297600       // 128*512 fork pivots
#define OFF_LOG    363136       // 128     per-row log(picked)
#define OFF_MI     363264       // 768 ints: [0..127]=p, [+128]=c, [+256]=x, [+384]=j0, [+512]=s, [+640]=pool off
#define OFF_POSMAP 364032       // 512 ints: site -> k or -1
#define OFF_MISC   364544       // ints: [0]=p127
#define OFF_FORK   364608       // fork snapshot pool

// ---------------------------------------------------------------- G = I - P P^T
__global__ void k_build(const float* __restrict__ P, float* __restrict__ ws) {
    __shared__ float Pr[32][129];
    __shared__ float Pc[32][129];
    int r0 = blockIdx.x * 32, c0 = blockIdx.y * 32, tid = threadIdx.x;
    for (int idx = tid; idx < 32 * 128; idx += 256) {
        int r = idx >> 7, t = idx & 127;
        Pr[r][t] = P[(r0 + r) * NN + t];
        Pc[r][t] = P[(c0 + r) * NN + t];
    }
    __syncthreads();
    int cl = tid & 31, rl0 = tid >> 5;
    for (int e = 0; e < 4; ++e) {
        int rl = rl0 + e * 8;
        float acc = 0.0f;
#pragma unroll 8
        for (int t = 0; t < 128; ++t) acc = fmaf(Pr[rl][t], Pc[cl][t], acc);
        int gr = r0 + rl, gc = c0 + cl;
        ws[OFF_M + gr * DD + gc] = ((gr == gc) ? 1.0f : 0.0f) - acc;
    }
}

// ---------------------------------------------------------------- per-k metadata + shadow init
__global__ void k_meta(const int* __restrict__ pos, float* __restrict__ ws) {
    int* mi   = (int*)ws + OFF_MI;
    int* pm   = (int*)ws + OFF_POSMAP;
    int* misc = (int*)ws + OFF_MISC;
    __shared__ int sS[128];
    int k = threadIdx.x;           // blockDim.x == 128
    int p = pos[k];
    mi[k] = p;
    mi[128 + k] = (k == 0) ? 0 : (pos[k - 1] + 1);   // c_k = xmin_k
    int x = XBASE + k;                                // xmax_k
    mi[256 + k] = x;
    int j0 = (p >> 5) << 5;                           // fork start column (stage boundary)
    mi[384 + k] = j0;
    int s = x - j0;                                   // fork submatrix side
    mi[512 + k] = s;
    sS[k] = s * s;
    float g = ws[OFF_M + p * DD + p];
    ws[OFF_SHAD + k]  = g - 1.0f;
    ws[OFF_SSNAP + k] = g - 1.0f;                     // stage-0 snapshot
    for (int i = k; i < 512; i += 128) pm[i] = -1;
    __syncthreads();
    pm[p] = k;
    if (k == 0) {
        int acc = 0;
        for (int i = 0; i < 128; ++i) { mi[640 + i] = acc; acc += sS[i]; }
        misc[0] = pos[127];
    }
}

// ---------------------------------------------------------------- stage-0 fork snapshots (raw G regions)
__global__ void k_snap0(float* __restrict__ ws) {
    const int* mi = (const int*)ws + OFF_MI;
    int r0 = blockIdx.x * 32, c0 = blockIdx.y * 32, tid = threadIdx.x;
    int cl = tid & 31, rl0 = tid >> 5;
    for (int k = 0; k < 128; ++k) {
        if (mi[384 + k] != 0) continue;
        int x = mi[256 + k];
        if (r0 >= x || c0 >= x) continue;
        int s = mi[512 + k];
        float* buf = ws + OFF_FORK + mi[640 + k];
        for (int e = 0; e < 4; ++e) {
            int gr = r0 + rl0 + e * 8, gc = c0 + cl;
            if (gr < x && gc < x) buf[gr * s + gc] = ws[OFF_M + gr * DD + gc];
        }
    }
}

// ---------------------------------------------------------------- chain panel factorization (1 WG, panel-only)
__global__ void __launch_bounds__(512) k_panel(float* __restrict__ ws, int t) {
    const int* misc = (const int*)ws + OFF_MISC;
    int j0 = t * 32;
    if (j0 > misc[0]) return;
    const int* pm = (const int*)ws + OFF_POSMAP;
    __shared__ float pan[512][33];
    __shared__ float shad[128];
    __shared__ int   chf[32];
    int tid = threadIdx.x;
    int h = DD - j0;
    for (int idx = tid; idx < h * 32; idx += 512) {
        int r = idx >> 5, jj = idx & 31;
        pan[r][jj] = ws[OFF_M + (j0 + r) * DD + j0 + jj];
    }
    if (tid < 128) { float sv = ws[OFF_SHAD + tid]; shad[tid] = sv; ws[OFF_SSNAP + t * 128 + tid] = sv; }
    if (tid < 32) chf[tid] = pm[j0 + tid];
    __syncthreads();
    for (int jj = 0; jj < 32; ++jj) {
        // pivot: LDS broadcast read (final as of previous phase-B barrier)
        float d = pan[jj][jj];
        if (tid == 0) ws[OFF_CPIV + j0 + jj] = d;
        float pv = (chf[jj] >= 0) ? shad[chf[jj]] : d;
        // phase A: divide (multipliers)
        for (int r = jj + 1 + tid; r < h; r += 512) pan[r][jj] = pan[r][jj] / pv;
        __syncthreads();
        // phase B: panel trailing update (row-per-thread, no div/mod)
        for (int r = jj + 1 + tid; r < h; r += 512) {
            float m = pan[r][jj];
            for (int cc = jj + 1; cc < 32; ++cc)
                pan[r][cc] = fmaf(-m, pan[jj][cc], pan[r][cc]);
        }
        if (tid < 32 && tid > jj && chf[tid] >= 0)
            shad[chf[tid]] = fmaf(-pan[tid][jj], pan[jj][tid], shad[chf[tid]]);
        __syncthreads();
    }
    // store FULL panel block (L11/U11 rows included: trail needs L11 for the U12 solve)
    for (int idx = tid; idx < h * 32; idx += 512) {
        int r = idx >> 5, jj = idx & 31;
        ws[OFF_LP + (j0 + r) * 32 + jj] = pan[r][jj];
    }
    if (tid < 128) ws[OFF_SHAD + tid] = shad[tid];
}

// ------------------------------------- chain trailing update (+in-block U12 solve) + next-stage snapshots
__global__ void k_trail(float* __restrict__ ws, int t) {
    const int* misc = (const int*)ws + OFF_MISC;
    int j0 = t * 32, jn = j0 + 32;
    if (jn > misc[0]) return;
    const int* mi = (const int*)ws + OFF_MI;
    const int* pm = (const int*)ws + OFF_POSMAP;
    int r0 = blockIdx.x * 32, c0 = blockIdx.y * 32, tid = threadIdx.x;
    if (r0 < jn || c0 < jn) return;
    __shared__ float Mt[32][33], Lt[32][33], Ut[32][33], L11[32][33];
    int cl = tid & 31, rl0 = tid >> 5;
    for (int e = 0; e < 4; ++e) {
        int rl = rl0 + e * 8;
        Mt[rl][cl]  = ws[OFF_M + (r0 + rl) * DD + c0 + cl];
        Lt[rl][cl]  = ws[OFF_LP + (r0 + rl) * 32 + cl];
        L11[rl][cl] = ws[OFF_LP + (j0 + rl) * 32 + cl];
        Ut[rl][cl]  = ws[OFF_M + (j0 + rl) * DD + c0 + cl];   // A12 tile (stage-(t-1) state)
    }
    __syncthreads();
    // U12 tile via left-looking triangular solve: identical per-element fp-op sequence
    // as the old right-looking strip (updates applied in ascending column order).
    if (tid < 32) {
        for (int jj = 1; jj < 32; ++jj) {
            float acc = Ut[jj][tid];
            for (int c = 0; c < jj; ++c) acc = fmaf(-L11[jj][c], Ut[c][tid], acc);
            Ut[jj][tid] = acc;
        }
    }
    __syncthreads();
    for (int e = 0; e < 4; ++e) {
        int rl = rl0 + e * 8;
        float acc = Mt[rl][cl];
#pragma unroll
        for (int jj = 0; jj < 32; ++jj) acc = fmaf(-Lt[rl][jj], Ut[jj][cl], acc);
        Mt[rl][cl] = acc;
        int gr = r0 + rl, gc = c0 + cl;
        if (gr == gc) {                               // shadow gets identical ordered update chain
            int kk = pm[gr];
            if (kk >= 0) {
                float sv = ws[OFF_SHAD + kk];
#pragma unroll
                for (int jj = 0; jj < 32; ++jj) sv = fmaf(-Lt[rl][jj], Ut[jj][cl], sv);
                ws[OFF_SHAD + kk] = sv;
            }
        }
        ws[OFF_M + gr * DD + gc] = acc;
    }
    __syncthreads();
    // snapshot regions for forks starting at stage t+1
    for (int k = 0; k < 128; ++k) {
        if (mi[384 + k] != jn) continue;
        int x = mi[256 + k];
        if (r0 >= x || c0 >= x) continue;
        int s = mi[512 + k];
        float* buf = ws + OFF_FORK + mi[640 + k];
        for (int e = 0; e < 4; ++e) {
            int gr = r0 + rl0 + e * 8, gc = c0 + cl;
            if (gr < x && gc < x) buf[(gr - jn) * s + (gc - jn)] = Mt[rl0 + e * 8][cl];
        }
    }
}

// ---------------------------------------------------------------- per-row fork: blocked LU of snapshot
__global__ void __launch_bounds__(512) k_fork(float* __restrict__ ws) {
    const int* mi = (const int*)ws + OFF_MI;
    const int* pm = (const int*)ws + OFF_POSMAP;
    int k = blockIdx.x;
    int p = mi[k], x = mi[256 + k], j0 = mi[384 + k], s = mi[512 + k];
    if (p >= x - 1) return;
    float* buf = ws + OFF_FORK + mi[640 + k];
    float* fpv = ws + OFF_FPIV + k * DD;
    int tstage = j0 >> 5;
    __shared__ float fpan[416][33];
    __shared__ float fstrip[32][388];
    __shared__ float lsh[32];
    __shared__ int   chflag[32];
    int tid = threadIdx.x;
    if (tid < 32) {
        int g = j0 + tid;
        int kk = (g < DD) ? pm[g] : -1;
        chflag[tid] = (kk >= 0 && g < p) ? kk : -1;
        lsh[tid] = (kk >= 0 && g < p) ? ws[OFF_SSNAP + tstage * 128 + kk] : 0.0f;
    }
    __syncthreads();
    int xl = s - 1;                                   // local index of column x-1 (record-only)
    bool done = false;
    for (int pf0 = 0; pf0 < s && !done; pf0 += 32) {
        int pw = (s - pf0 < 32) ? (s - pf0) : 32;
        int hl = s - pf0;
        int wl = s - pf0 - pw;
        for (int idx = tid; idx < hl * pw; idx += 512) {
            int r = idx / pw, jj = idx % pw;
            fpan[r][jj] = buf[(pf0 + r) * s + pf0 + jj];
        }
        for (int idx = tid; idx < pw * wl; idx += 512) {
            int jj = idx / wl, cc = idx % wl;
            fstrip[jj][cc] = buf[(pf0 + jj) * s + pf0 + pw + cc];
        }
        __syncthreads();
        for (int jj = 0; jj < pw; ++jj) {
            int lc = pf0 + jj;
            int g = j0 + lc;
            float d = fpan[jj][jj];                   // broadcast read, final since last barrier
            if (tid == 0 && g > p) fpv[g] = d;        // A_k pivot at column g
            float pv = d;
            if (pf0 == 0 && chflag[jj] >= 0) pv = lsh[jj];
            if (lc >= xl) { done = true; break; }     // last pivot recorded
            // phase A: divide
            for (int r = jj + 1 + tid; r < hl; r += 512) fpan[r][jj] = fpan[r][jj] / pv;
            __syncthreads();
            // phase B: panel + strip updates (no div/mod in index math)
            for (int r = jj + 1 + tid; r < hl; r += 512) {
                float m = fpan[r][jj];
                for (int cc = jj + 1; cc < pw; ++cc)
                    fpan[r][cc] = fmaf(-m, fpan[jj][cc], fpan[r][cc]);
            }
            for (int rr = jj + 1; rr < pw; ++rr) {
                float m = fpan[rr][jj];
                for (int cc = tid; cc < wl; cc += 512)
                    fstrip[rr][cc] = fmaf(-m, fstrip[jj][cc], fstrip[rr][cc]);
            }
            if (pf0 == 0 && tid < 32 && tid > jj && chflag[tid] >= 0)
                lsh[tid] = fmaf(-fpan[tid][jj], fpan[jj][tid], lsh[tid]);
            __syncthreads();
        }
        if (done) break;
        // trailing GEMM update on global snapshot, 4x4 register tiles (pw==32 whenever wl>0)
        int tw = wl;
        if (tw > 0) {
            int ntr = (tw + 3) >> 2;
            int nt2 = ntr * ntr;
            for (int tile = tid; tile < nt2; tile += 512) {
                int ti = tile / ntr;
                int tr = ti << 2, tc = (tile - ti * ntr) << 2;
                int rb = pf0 + 32 + tr, cb = pf0 + 32 + tc;
                float acc[4][4];
                if (tr + 4 <= tw && tc + 4 <= tw) {   // interior fast path
#pragma unroll
                    for (int i = 0; i < 4; ++i)
#pragma unroll
                        for (int j = 0; j < 4; ++j) acc[i][j] = buf[(rb + i) * s + cb + j];
#pragma unroll 8
                    for (int jj = 0; jj < 32; ++jj) {
                        float a0 = fpan[32 + tr + 0][jj], a1 = fpan[32 + tr + 1][jj];
                        float a2 = fpan[32 + tr + 2][jj], a3 = fpan[32 + tr + 3][jj];
                        float b0 = fstrip[jj][tc + 0], b1 = fstrip[jj][tc + 1];
                        float b2 = fstrip[jj][tc + 2], b3 = fstrip[jj][tc + 3];
                        acc[0][0] = fmaf(-a0, b0, acc[0][0]); acc[0][1] = fmaf(-a0, b1, acc[0][1]);
                        acc[0][2] = fmaf(-a0, b2, acc[0][2]); acc[0][3] = fmaf(-a0, b3, acc[0][3]);
                        acc[1][0] = fmaf(-a1, b0, acc[1][0]); acc[1][1] = fmaf(-a1, b1, acc[1][1]);
                        acc[1][2] = fmaf(-a1, b2, acc[1][2]); acc[1][3] = fmaf(-a1, b3, acc[1][3]);
                        acc[2][0] = fmaf(-a2, b0, acc[2][0]); acc[2][1] = fmaf(-a2, b1, acc[2][1]);
                        acc[2][2] = fmaf(-a2, b2, acc[2][2]); acc[2][3] = fmaf(-a2, b3, acc[2][3]);
                        acc[3][0] = fmaf(-a3, b0, acc[3][0]); acc[3][1] = fmaf(-a3, b1, acc[3][1]);
                        acc[3][2] = fmaf(-a3, b2, acc[3][2]); acc[3][3] = fmaf(-a3, b3, acc[3][3]);
                    }
#pragma unroll
                    for (int i = 0; i < 4; ++i)
#pragma unroll
                        for (int j = 0; j < 4; ++j) buf[(rb + i) * s + cb + j] = acc[i][j];
                } else {                               // edge tile, guarded
#pragma unroll
                    for (int i = 0; i < 4; ++i)
#pragma unroll
                        for (int j = 0; j < 4; ++j)
                            acc[i][j] = (tr + i < tw && tc + j < tw) ? buf[(rb + i) * s + cb + j] : 0.0f;
                    for (int jj = 0; jj < 32; ++jj) {
                        float a[4], b[4];
#pragma unroll
                        for (int i = 0; i < 4; ++i) {
                            int rr = 32 + tr + i; a[i] = fpan[rr < hl ? rr : (hl - 1)][jj];
                        }
#pragma unroll
                        for (int j = 0; j < 4; ++j) {
                            int ccc = tc + j; b[j] = fstrip[jj][ccc < tw ? ccc : (tw - 1)];
                        }
#pragma unroll
                        for (int i = 0; i < 4; ++i)
#pragma unroll
                            for (int j = 0; j < 4; ++j) acc[i][j] = fmaf(-a[i], b[j], acc[i][j]);
                    }
#pragma unroll
                    for (int i = 0; i < 4; ++i)
#pragma unroll
                        for (int j = 0; j < 4; ++j)
                            if (tr + i < tw && tc + j < tw) buf[(rb + i) * s + cb + j] = acc[i][j];
                }
            }
        }
        __syncthreads();
    }
}

// ---------------------------------------------------------------- probs rows: cumprod + threshold + log term
__global__ void k_epilogue(float* __restrict__ ws, float* __restrict__ out) {
    const int* mi = (const int*)ws + OFF_MI;
    int k = blockIdx.x, tid = threadIdx.x;
    __shared__ float row[512];
    __shared__ float pivs[512];
    int c = mi[128 + k], p = mi[k], x = mi[256 + k];
    for (int i = tid; i < 512; i += 256) {
        row[i] = 0.0f;
        pivs[i] = (i <= p) ? ws[OFF_CPIV + i] : ws[OFF_FPIV + k * DD + i];
    }
    __syncthreads();
    if (tid == 0) {                                   // exact serial fp order (matches reference cumprod)
        float cp = 1.0f;
        for (int i = c; i < x; ++i) {
            float pv = pivs[i];
            float pr = cp * (1.0f - pv);
            row[i] = (fabsf(pr) > 1e-15f) ? pr : 0.0f;
            cp = cp * pv;
        }
        ws[OFF_LOG + k] = logf(row[p]);
    }
    __syncthreads();
    for (int i = tid; i < 512; i += 256) out[k * DD + i] = row[i];
}

__global__ void k_logsum(float* __restrict__ ws, float* __restrict__ out) {
    __shared__ float lv[128];
    int tid = threadIdx.x;
    if (tid < 64) { lv[tid] = ws[OFF_LOG + tid]; lv[tid + 64] = ws[OFF_LOG + tid + 64]; }
    __syncthreads();
    if (tid == 0) {
        double sacc = 0.0;
        for (int i = 0; i < 128; ++i) sacc += (double)lv[i];
        out[65536] = (float)sacc;
    }
}

// ----------------------------------------------------------------
extern "C" void kernel_launch(void* const* d_in, const int* in_sizes, int n_in,
                              void* d_out, int out_size, void* d_ws, size_t ws_size,
                              hipStream_t stream) {
    const float* P   = (const float*)d_in[0];
    const int*   pos = (const int*)d_in[1];
    float* ws  = (float*)d_ws;
    float* out = (float*)d_out;

    k_build<<<dim3(16, 16), 256, 0, stream>>>(P, ws);
    k_meta<<<1, 128, 0, stream>>>(pos, ws);
    k_snap0<<<dim3(16, 16), 256, 0, stream>>>(ws);
    for (int t = 0; t < 16; ++t) {
        k_panel<<<1, 512, 0, stream>>>(ws, t);
        if (t < 15) k_trail<<<dim3(16, 16), 256, 0, stream>>>(ws, t);
    }
    k_fork<<<128, 512, 0, stream>>>(ws);
    k_epilogue<<<128, 256, 0, stream>>>(ws, out);
    k_logsum<<<1, 64, 0, stream>>>(ws, out);
}

// Round 3
// 2317.991 us; speedup vs baseline: 1.2927x; 1.2927x over previous
//
#include <hip/hip_runtime.h>
#include <math.h>

// Problem constants
#define DD 512
#define NN 128
#define XBASE 385   // D - N + 1 ; xmax_k = XBASE + k

// Workspace layout (in 4-byte elements)
#define OFF_M      0            // 512*512 chain matrix
#define OFF_LP     262144       // 512*32  L21 rows of current stage
#define OFF_UP     278528       // 32*512  U12 strip of current stage
#define OFF_CPIV   294912       // 512     chain pivots (unshadowed diag at elimination time)
#define OFF_SHAD   295424       // 128     running shadow diagonals
#define OFF_SSNAP  295552       // 16*128  shadow snapshot at start of each stage
#define OFF_FPIV   297600       // 128*512 fork pivots
#define OFF_LOG    363136       // 128     per-row log(picked)
#define OFF_MI     363264       // 768 ints: [0..127]=p, [+128]=c, [+256]=x, [+384]=j0, [+512]=s, [+640]=pool off
#define OFF_POSMAP 364032       // 512 ints: site -> k or -1
#define OFF_MISC   364544       // ints: [0]=p127
#define OFF_FORK   364608       // fork snapshot pool (~25 MB)

// ---------------------------------------------------------------- wave0 32x32 block LU (lanes 0-31, register rows, shfl broadcast)
// a[c] = row `lane` of the block. Eliminates cols j < elim, records diag d for cols j <= recl.
// Pivot for col j = shadow (lane j's sh) if bit j of shmask, else d. Identical per-element
// fp-op order as unblocked right-looking elimination restricted to the block.
template<bool RECALL>
__device__ __forceinline__ float w0_block_lu(float (&a)[32], float sh,
    unsigned long long shmask, int elim, int recl,
    float* __restrict__ pvsL, float (*dblkL)[33],
    float* __restrict__ recp, int gbase, int gmin, int lane)
{
    bool mine = (shmask >> lane) & 1ull;
#pragma unroll
    for (int j = 0; j < 32; ++j) {
        if (j > recl) break;
        float d  = __shfl(a[j], j);
        float sj = __shfl(sh, j);
        if (lane == 0) {
            int g = gbase + j;
            if (RECALL || g > gmin) recp[g] = d;
        }
        if (j >= elim) break;
        float pv = ((shmask >> j) & 1ull) ? sj : d;
        if (lane == 0) pvsL[j] = pv;
        bool below = lane > j;
        if (below) a[j] = a[j] / pv;
        float m = a[j];
#pragma unroll
        for (int c = j + 1; c < 32; ++c) {
            float bj = __shfl(a[c], j);
            if (below) {
                a[c] = fmaf(-m, bj, a[c]);
                if (mine && lane == c) sh = fmaf(-m, bj, sh);
            }
        }
    }
#pragma unroll
    for (int c = 0; c < 32; ++c) dblkL[lane][c] = a[c];
    return sh;
}

// ---------------------------------------------------------------- G = I - P P^T
__global__ void k_build(const float* __restrict__ P, float* __restrict__ ws) {
    __shared__ float Pr[32][129];
    __shared__ float Pc[32][129];
    int r0 = blockIdx.x * 32, c0 = blockIdx.y * 32, tid = threadIdx.x;
    for (int idx = tid; idx < 32 * 128; idx += 256) {
        int r = idx >> 7, t = idx & 127;
        Pr[r][t] = P[(r0 + r) * NN + t];
        Pc[r][t] = P[(c0 + r) * NN + t];
    }
    __syncthreads();
    int cl = tid & 31, rl0 = tid >> 5;
    for (int e = 0; e < 4; ++e) {
        int rl = rl0 + e * 8;
        float acc = 0.0f;
#pragma unroll 8
        for (int t = 0; t < 128; ++t) acc = fmaf(Pr[rl][t], Pc[cl][t], acc);
        int gr = r0 + rl, gc = c0 + cl;
        ws[OFF_M + gr * DD + gc] = ((gr == gc) ? 1.0f : 0.0f) - acc;
    }
}

// ---------------------------------------------------------------- per-k metadata + shadow init
__global__ void k_meta(const int* __restrict__ pos, float* __restrict__ ws) {
    int* mi   = (int*)ws + OFF_MI;
    int* pm   = (int*)ws + OFF_POSMAP;
    int* misc = (int*)ws + OFF_MISC;
    __shared__ int sS[128];
    int k = threadIdx.x;           // blockDim.x == 128
    int p = pos[k];
    mi[k] = p;
    mi[128 + k] = (k == 0) ? 0 : (pos[k - 1] + 1);   // c_k = xmin_k
    int x = XBASE + k;                                // xmax_k
    mi[256 + k] = x;
    int j0 = (p >> 5) << 5;                           // fork start column (stage boundary)
    mi[384 + k] = j0;
    int s = x - j0;                                   // fork submatrix side
    mi[512 + k] = s;
    sS[k] = s * s;
    float g = ws[OFF_M + p * DD + p];
    ws[OFF_SHAD + k]  = g - 1.0f;
    ws[OFF_SSNAP + k] = g - 1.0f;                     // stage-0 snapshot
    for (int i = k; i < 512; i += 128) pm[i] = -1;
    __syncthreads();
    pm[p] = k;
    if (k == 0) {
        int acc = 0;
        for (int i = 0; i < 128; ++i) { mi[640 + i] = acc; acc += sS[i]; }
        misc[0] = pos[127];
    }
}

// ---------------------------------------------------------------- stage-0 fork snapshots (raw G regions)
__global__ void k_snap0(float* __restrict__ ws) {
    const int* mi = (const int*)ws + OFF_MI;
    int r0 = blockIdx.x * 32, c0 = blockIdx.y * 32, tid = threadIdx.x;
    int cl = tid & 31, rl0 = tid >> 5;
    for (int k = 0; k < 128; ++k) {
        if (mi[384 + k] != 0) continue;
        int x = mi[256 + k];
        if (r0 >= x || c0 >= x) continue;
        int s = mi[512 + k];
        float* buf = ws + OFF_FORK + mi[640 + k];
        for (int e = 0; e < 4; ++e) {
            int gr = r0 + rl0 + e * 8, gc = c0 + cl;
            if (gr < x && gc < x) buf[gr * s + gc] = ws[OFF_M + gr * DD + gc];
        }
    }
}

// ---------------------------------------------------------------- chain panel: wave0 block LU + parallel L21/U12 solves
__global__ void __launch_bounds__(1024) k_panel(float* __restrict__ ws, int t) {
    const int* misc = (const int*)ws + OFF_MISC;
    int j0 = t * 32;
    if (j0 > misc[0]) return;
    const int* pm = (const int*)ws + OFF_POSMAP;
    __shared__ float dblk[32][33];
    __shared__ float pvs[32];
    __shared__ float shadL[128];
    __shared__ int   chfL[32];
    int tid = threadIdx.x;
    int jn = j0 + 32, w = DD - jn;
    if (tid < 128) { float sv = ws[OFF_SHAD + tid]; shadL[tid] = sv; ws[OFF_SSNAP + t * 128 + tid] = sv; }
    if (tid < 32) chfL[tid] = pm[j0 + tid];
    __syncthreads();
    if (tid < 32) {
        float a[32];
#pragma unroll
        for (int c = 0; c < 32; ++c) a[c] = ws[OFF_M + (size_t)(j0 + tid) * DD + j0 + c];
        int cf = chfL[tid];
        float sh = (cf >= 0) ? shadL[cf] : 0.0f;
        unsigned long long bm = __ballot(cf >= 0);
        sh = w0_block_lu<true>(a, sh, bm, 32, 31, pvs, dblk, ws + OFF_CPIV, j0, -1, tid);
        if (cf >= 0) ws[OFF_SHAD + cf] = sh;
    }
    __syncthreads();
    // phase P: L21 rows (w tasks) + U12 cols (w tasks), all independent, no sync
    for (int task = tid; task < 2 * w; task += 1024) {
        if (task < w) {                               // L21 row r = jn+task
            int r = jn + task;
            const float* src = ws + OFF_M + (size_t)r * DD + j0;
            float a[32];
#pragma unroll
            for (int c = 0; c < 32; ++c) a[c] = src[c];
#pragma unroll
            for (int j = 0; j < 32; ++j) {
                float tv = a[j];
                for (int c = 0; c < j; ++c) tv = fmaf(-a[c], dblk[c][j], tv);
                a[j] = tv / pvs[j];
            }
            float* dst = ws + OFF_LP + (size_t)r * 32;
#pragma unroll
            for (int c = 0; c < 32; ++c) dst[c] = a[c];
        } else {                                      // U12 col
            int col = jn + (task - w);
            float v[32];
#pragma unroll
            for (int j = 0; j < 32; ++j) v[j] = ws[OFF_M + (size_t)(j0 + j) * DD + col];
#pragma unroll
            for (int j = 1; j < 32; ++j) {
                float tv = v[j];
                for (int c = 0; c < j; ++c) tv = fmaf(-dblk[j][c], v[c], tv);
                v[j] = tv;
            }
#pragma unroll
            for (int j = 0; j < 32; ++j) ws[OFF_UP + j * DD + col] = v[j];
        }
    }
}

// ------------------------------------- chain trailing GEMM (pure) + shadow updates + next-stage snapshots
__global__ void k_trail(float* __restrict__ ws, int t) {
    const int* misc = (const int*)ws + OFF_MISC;
    int j0 = t * 32, jn = j0 + 32;
    if (jn > misc[0]) return;
    const int* mi = (const int*)ws + OFF_MI;
    const int* pm = (const int*)ws + OFF_POSMAP;
    int r0 = blockIdx.x * 32, c0 = blockIdx.y * 32, tid = threadIdx.x;
    if (r0 < jn || c0 < jn) return;
    __shared__ float Mt[32][33], Lt[32][33], Ut[32][33];
    int cl = tid & 31, rl0 = tid >> 5;
    for (int e = 0; e < 4; ++e) {
        int rl = rl0 + e * 8;
        Mt[rl][cl] = ws[OFF_M + (r0 + rl) * DD + c0 + cl];
        Lt[rl][cl] = ws[OFF_LP + (r0 + rl) * 32 + cl];
        Ut[rl][cl] = ws[OFF_UP + rl * DD + c0 + cl];
    }
    __syncthreads();
    for (int e = 0; e < 4; ++e) {
        int rl = rl0 + e * 8;
        float acc = Mt[rl][cl];
#pragma unroll
        for (int jj = 0; jj < 32; ++jj) acc = fmaf(-Lt[rl][jj], Ut[jj][cl], acc);
        Mt[rl][cl] = acc;
        int gr = r0 + rl, gc = c0 + cl;
        if (gr == gc) {                               // shadow gets identical ordered update chain
            int kk = pm[gr];
            if (kk >= 0) {
                float sv = ws[OFF_SHAD + kk];
#pragma unroll
                for (int jj = 0; jj < 32; ++jj) sv = fmaf(-Lt[rl][jj], Ut[jj][cl], sv);
                ws[OFF_SHAD + kk] = sv;
            }
        }
        ws[OFF_M + gr * DD + gc] = acc;
    }
    __syncthreads();
    // snapshot regions for forks starting at stage t+1
    for (int k = 0; k < 128; ++k) {
        if (mi[384 + k] != jn) continue;
        int x = mi[256 + k];
        if (r0 >= x || c0 >= x) continue;
        int s = mi[512 + k];
        float* buf = ws + OFF_FORK + mi[640 + k];
        for (int e = 0; e < 4; ++e) {
            int gr = r0 + rl0 + e * 8, gc = c0 + cl;
            if (gr < x && gc < x) buf[(gr - jn) * s + (gc - jn)] = Mt[rl0 + e * 8][cl];
        }
    }
}

// ---------------------------------------------------------------- per-row fork: blocked LU, per-stage sync only
__global__ void __launch_bounds__(1024) k_fork(float* __restrict__ ws) {
    const int* mi = (const int*)ws + OFF_MI;
    const int* pm = (const int*)ws + OFF_POSMAP;
    int k = blockIdx.x;
    int p = mi[k], x = mi[256 + k], j0 = mi[384 + k], s = mi[512 + k];
    if (p >= x - 1) return;
    float* buf = ws + OFF_FORK + mi[640 + k];
    float* fpv = ws + OFF_FPIV + k * DD;
    int tstage = j0 >> 5;
    __shared__ float dblk[32][33];
    __shared__ float pvs[32];
    __shared__ float fpan[388][33];                   // L21 rows (local), max 384
    __shared__ float fstrip[32][388];                 // U12 strip
    int tid = threadIdx.x;
    int xl = s - 1;                                   // local index of last needed column (record-only)
    for (int pf0 = 0;; pf0 += 32) {
        int rem = xl - pf0;
        // ---- Phase S: wave0 lanes 0-31: diag-block LU (no barriers inside)
        if (tid < 32) {
            float a[32];
#pragma unroll
            for (int c = 0; c < 32; ++c) {
                int rr = pf0 + tid, cc = pf0 + c;
                a[c] = (rr <= xl && cc <= xl) ? buf[(size_t)rr * s + cc] : 0.0f;
            }
            float sh = 0.0f;
            unsigned long long bm = 0ull;
            if (pf0 == 0) {
                int g = j0 + tid;
                int kk = pm[g];
                bool ch = (kk >= 0 && g < p);         // chosen cols before p use shadow pivots
                if (ch) sh = ws[OFF_SSNAP + tstage * 128 + kk];
                bm = __ballot(ch);
            }
            int elim = rem < 32 ? rem : 32;
            int recl = rem < 31 ? rem : 31;
            w0_block_lu<false>(a, sh, bm, elim, recl, pvs, dblk, fpv, j0 + pf0, p, tid);
        }
        if (rem < 32) break;                          // uniform: final (partial) block handled, done
        __syncthreads();
        int tw = s - pf0 - 32;                        // square trailing size (<=384)
        // ---- Phase P: L21 rows (tid<tw) and U12 cols (tid-512<tw), independent, no sync
        if (tid < tw) {
            int r = pf0 + 32 + tid;
            const float* src = buf + (size_t)r * s + pf0;
            float a[32];
#pragma unroll
            for (int c = 0; c < 32; ++c) a[c] = src[c];
#pragma unroll
            for (int j = 0; j < 32; ++j) {
                float tv = a[j];
                for (int c = 0; c < j; ++c) tv = fmaf(-a[c], dblk[c][j], tv);
                a[j] = tv / pvs[j];
            }
#pragma unroll
            for (int c = 0; c < 32; ++c) fpan[tid][c] = a[c];
        } else if (tid >= 512 && tid < 512 + tw) {
            int u = tid - 512;
            int col = pf0 + 32 + u;
            float v[32];
#pragma unroll
            for (int j = 0; j < 32; ++j) v[j] = buf[(size_t)(pf0 + j) * s + col];
#pragma unroll
            for (int j = 1; j < 32; ++j) {
                float tv = v[j];
                for (int c = 0; c < j; ++c) tv = fmaf(-dblk[j][c], v[c], tv);
                v[j] = tv;
            }
#pragma unroll
            for (int j = 0; j < 32; ++j) fstrip[j][u] = v[j];
        }
        __syncthreads();
        // ---- Phase G: trailing GEMM  buf -= fpan * fstrip  (4x4 register tiles)
        {
            int ntr = (tw + 3) >> 2;
            int nt2 = ntr * ntr;
            for (int tile = tid; tile < nt2; tile += 1024) {
                int ti = tile / ntr;
                int tr = ti << 2, tc = (tile - ti * ntr) << 2;
                int rb = pf0 + 32 + tr, cb = pf0 + 32 + tc;
                float acc[4][4];
                if (tr + 4 <= tw && tc + 4 <= tw) {   // interior fast path
#pragma unroll
                    for (int i = 0; i < 4; ++i)
#pragma unroll
                        for (int j = 0; j < 4; ++j) acc[i][j] = buf[(size_t)(rb + i) * s + cb + j];
#pragma unroll 8
                    for (int jj = 0; jj < 32; ++jj) {
                        float a0 = fpan[tr + 0][jj], a1 = fpan[tr + 1][jj];
                        float a2 = fpan[tr + 2][jj], a3 = fpan[tr + 3][jj];
                        float b0 = fstrip[jj][tc + 0], b1 = fstrip[jj][tc + 1];
                        float b2 = fstrip[jj][tc + 2], b3 = fstrip[jj][tc + 3];
                        acc[0][0] = fmaf(-a0, b0, acc[0][0]); acc[0][1] = fmaf(-a0, b1, acc[0][1]);
                        acc[0][2] = fmaf(-a0, b2, acc[0][2]); acc[0][3] = fmaf(-a0, b3, acc[0][3]);
                        acc[1][0] = fmaf(-a1, b0, acc[1][0]); acc[1][1] = fmaf(-a1, b1, acc[1][1]);
                        acc[1][2] = fmaf(-a1, b2, acc[1][2]); acc[1][3] = fmaf(-a1, b3, acc[1][3]);
                        acc[2][0] = fmaf(-a2, b0, acc[2][0]); acc[2][1] = fmaf(-a2, b1, acc[2][1]);
                        acc[2][2] = fmaf(-a2, b2, acc[2][2]); acc[2][3] = fmaf(-a2, b3, acc[2][3]);
                        acc[3][0] = fmaf(-a3, b0, acc[3][0]); acc[3][1] = fmaf(-a3, b1, acc[3][1]);
                        acc[3][2] = fmaf(-a3, b2, acc[3][2]); acc[3][3] = fmaf(-a3, b3, acc[3][3]);
                    }
#pragma unroll
                    for (int i = 0; i < 4; ++i)
#pragma unroll
                        for (int j = 0; j < 4; ++j) buf[(size_t)(rb + i) * s + cb + j] = acc[i][j];
                } else {                               // edge tile, guarded per element
#pragma unroll
                    for (int i = 0; i < 4; ++i)
#pragma unroll
                        for (int j = 0; j < 4; ++j)
                            acc[i][j] = (tr + i < tw && tc + j < tw) ? buf[(size_t)(rb + i) * s + cb + j] : 0.0f;
                    for (int jj = 0; jj < 32; ++jj) {
                        float a[4], b[4];
#pragma unroll
                        for (int i = 0; i < 4; ++i) {
                            int rr = tr + i; a[i] = fpan[rr < tw ? rr : (tw - 1)][jj];
                        }
#pragma unroll
                        for (int j = 0; j < 4; ++j) {
                            int ccc = tc + j; b[j] = fstrip[jj][ccc < tw ? ccc : (tw - 1)];
                        }
#pragma unroll
                        for (int i = 0; i < 4; ++i)
#pragma unroll
                            for (int j = 0; j < 4; ++j) acc[i][j] = fmaf(-a[i], b[j], acc[i][j]);
                    }
#pragma unroll
                    for (int i = 0; i < 4; ++i)
#pragma unroll
                        for (int j = 0; j < 4; ++j)
                            if (tr + i < tw && tc + j < tw) buf[(size_t)(rb + i) * s + cb + j] = acc[i][j];
                }
            }
        }
        __syncthreads();
    }
}

// ---------------------------------------------------------------- probs rows: cumprod + threshold + log term
__global__ void k_epilogue(float* __restrict__ ws, float* __restrict__ out) {
    const int* mi = (const int*)ws + OFF_MI;
    int k = blockIdx.x, tid = threadIdx.x;
    __shared__ float row[512];
    __shared__ float pivs[512];
    int c = mi[128 + k], p = mi[k], x = mi[256 + k];
    for (int i = tid; i < 512; i += 256) {
        row[i] = 0.0f;
        pivs[i] = (i <= p) ? ws[OFF_CPIV + i] : ws[OFF_FPIV + k * DD + i];
    }
    __syncthreads();
    if (tid == 0) {                                   // exact serial fp order (matches reference cumprod)
        float cp = 1.0f;
        for (int i = c; i < x; ++i) {
            float pv = pivs[i];
            float pr = cp * (1.0f - pv);
            row[i] = (fabsf(pr) > 1e-15f) ? pr : 0.0f;
            cp = cp * pv;
        }
        ws[OFF_LOG + k] = logf(row[p]);
    }
    __syncthreads();
    for (int i = tid; i < 512; i += 256) out[k * DD + i] = row[i];
}

__global__ void k_logsum(float* __restrict__ ws, float* __restrict__ out) {
    __shared__ float lv[128];
    int tid = threadIdx.x;
    if (tid < 64) { lv[tid] = ws[OFF_LOG + tid]; lv[tid + 64] = ws[OFF_LOG + tid + 64]; }
    __syncthreads();
    if (tid == 0) {
        double sacc = 0.0;
        for (int i = 0; i < 128; ++i) sacc += (double)lv[i];
        out[65536] = (float)sacc;
    }
}

// ----------------------------------------------------------------
extern "C" void kernel_launch(void* const* d_in, const int* in_sizes, int n_in,
                              void* d_out, int out_size, void* d_ws, size_t ws_size,
                              hipStream_t stream) {
    const float* P   = (const float*)d_in[0];
    const int*   pos = (const int*)d_in[1];
    float* ws  = (float*)d_ws;
    float* out = (float*)d_out;

    k_build<<<dim3(16, 16), 256, 0, stream>>>(P, ws);
    k_meta<<<1, 128, 0, stream>>>(pos, ws);
    k_snap0<<<dim3(16, 16), 256, 0, stream>>>(ws);
    for (int t = 0; t < 16; ++t) {
        k_panel<<<1, 1024, 0, stream>>>(ws, t);
        if (t < 15) k_trail<<<dim3(16, 16), 256, 0, stream>>>(ws, t);
    }
    k_fork<<<128, 1024, 0, stream>>>(ws);
    k_epilogue<<<128, 256, 0, stream>>>(ws, out);
    k_logsum<<<1, 64, 0, stream>>>(ws, out);
}

// Round 5
// 2135.689 us; speedup vs baseline: 1.4031x; 1.0854x over previous
//
#include <hip/hip_runtime.h>
#include <math.h>

// Problem constants
#define DD 512
#define NN 128
#define XBASE 385   // D - N + 1 ; xmax_k = XBASE + k

// Workspace layout (in 4-byte elements)
#define OFF_M      0            // 512*512 chain matrix
#define OFF_LP     262144       // 512*32  L21 rows of current stage
#define OFF_UP     278528       // 32*512  U12 strip of current stage
#define OFF_CPIV   294912       // 512     chain pivots (unshadowed diag at elimination time)
#define OFF_SHAD   295424       // 128     running shadow diagonals
#define OFF_SSNAP  295552       // 16*128  shadow snapshot at start of each stage
#define OFF_FPIV   297600       // 128*512 fork pivots
#define OFF_LOG    363136       // 128     per-row log(picked)
#define OFF_MI     363264       // 768 ints: [0..127]=p, [+128]=c, [+256]=x, [+384]=j0, [+512]=s, [+640]=pool off
#define OFF_POSMAP 364032       // 512 ints: site -> k or -1
#define OFF_MISC   364544       // ints: [0]=p127
#define OFF_FORK   364608       // fork snapshot pool (~25 MB)

// ---------------------------------------------------------------- wave0 32x32 block LU (lanes 0-31, register rows, shfl broadcast)
// Identical per-element fp-op order as unblocked right-looking elimination restricted to the block.
// Writes both dblk (row-major) and dblkT (transposed), rows padded to 36 floats (16B-aligned rows).
template<bool RECALL>
__device__ __forceinline__ float w0_block_lu(float (&a)[32], float sh,
    unsigned long long shmask, int elim, int recl,
    float* __restrict__ pvsL, float (*dblkL)[36], float (*dblkTL)[36],
    float* __restrict__ recp, int gbase, int gmin, int lane)
{
    bool mine = (shmask >> lane) & 1ull;
#pragma unroll
    for (int j = 0; j < 32; ++j) {
        if (j > recl) break;
        float d  = __shfl(a[j], j);
        float sj = __shfl(sh, j);
        if (lane == 0) {
            int g = gbase + j;
            if (RECALL || g > gmin) recp[g] = d;
        }
        if (j >= elim) break;
        float pv = ((shmask >> j) & 1ull) ? sj : d;
        if (lane == 0) pvsL[j] = pv;
        bool below = lane > j;
        if (below) a[j] = a[j] / pv;
        float m = a[j];
#pragma unroll
        for (int c = j + 1; c < 32; ++c) {
            float bj = __shfl(a[c], j);
            if (below) {
                a[c] = fmaf(-m, bj, a[c]);
                if (mine && lane == c) sh = fmaf(-m, bj, sh);
            }
        }
    }
#pragma unroll
    for (int c = 0; c < 32; ++c) { dblkL[lane][c] = a[c]; dblkTL[c][lane] = a[c]; }
    return sh;
}

// -------- right-looking L21 row solve: bit-identical op sequence to left-looking
// (each a[j] receives updates in ascending c, then divides at c==j). float4 dblk reads.
__device__ __forceinline__ void solve_L21_row(float (&a)[32], const float (*dblk)[36],
                                              const float* __restrict__ pvs) {
#pragma unroll
    for (int c = 0; c < 32; ++c) {
        a[c] = a[c] / pvs[c];
        float m = a[c];
        int j = c + 1;
#pragma unroll
        for (; (j & 3) && j < 32; ++j) a[j] = fmaf(-m, dblk[c][j], a[j]);
#pragma unroll
        for (; j + 3 < 32; j += 4) {
            const float4 u = *(const float4*)&dblk[c][j];
            a[j+0] = fmaf(-m, u.x, a[j+0]); a[j+1] = fmaf(-m, u.y, a[j+1]);
            a[j+2] = fmaf(-m, u.z, a[j+2]); a[j+3] = fmaf(-m, u.w, a[j+3]);
        }
    }
}

// -------- right-looking U12 col solve (no divide), float4 dblkT reads; bit-identical order.
__device__ __forceinline__ void solve_U12_col(float (&v)[32], const float (*dblkT)[36]) {
#pragma unroll
    for (int c = 0; c < 31; ++c) {
        float vc = v[c];
        int j = c + 1;
#pragma unroll
        for (; (j & 3) && j < 32; ++j) v[j] = fmaf(-dblkT[c][j], vc, v[j]);
#pragma unroll
        for (; j + 3 < 32; j += 4) {
            const float4 u = *(const float4*)&dblkT[c][j];
            v[j+0] = fmaf(-u.x, vc, v[j+0]); v[j+1] = fmaf(-u.y, vc, v[j+1]);
            v[j+2] = fmaf(-u.z, vc, v[j+2]); v[j+3] = fmaf(-u.w, vc, v[j+3]);
        }
    }
}

// ---------------------------------------------------------------- G = I - P P^T
__global__ void k_build(const float* __restrict__ P, float* __restrict__ ws) {
    __shared__ float Pr[32][129];
    __shared__ float Pc[32][129];
    int r0 = blockIdx.x * 32, c0 = blockIdx.y * 32, tid = threadIdx.x;
    for (int idx = tid; idx < 32 * 128; idx += 256) {
        int r = idx >> 7, t = idx & 127;
        Pr[r][t] = P[(r0 + r) * NN + t];
        Pc[r][t] = P[(c0 + r) * NN + t];
    }
    __syncthreads();
    int cl = tid & 31, rl0 = tid >> 5;
    for (int e = 0; e < 4; ++e) {
        int rl = rl0 + e * 8;
        float acc = 0.0f;
#pragma unroll 8
        for (int t = 0; t < 128; ++t) acc = fmaf(Pr[rl][t], Pc[cl][t], acc);
        int gr = r0 + rl, gc = c0 + cl;
        ws[OFF_M + gr * DD + gc] = ((gr == gc) ? 1.0f : 0.0f) - acc;
    }
}

// ---------------------------------------------------------------- per-k metadata + shadow init
__global__ void k_meta(const int* __restrict__ pos, float* __restrict__ ws) {
    int* mi   = (int*)ws + OFF_MI;
    int* pm   = (int*)ws + OFF_POSMAP;
    int* misc = (int*)ws + OFF_MISC;
    __shared__ int sS[128];
    int k = threadIdx.x;           // blockDim.x == 128
    int p = pos[k];
    mi[k] = p;
    mi[128 + k] = (k == 0) ? 0 : (pos[k - 1] + 1);   // c_k = xmin_k
    int x = XBASE + k;                                // xmax_k
    mi[256 + k] = x;
    int j0 = (p >> 5) << 5;                           // fork start column (stage boundary)
    mi[384 + k] = j0;
    int s = x - j0;                                   // fork submatrix side (<=385)
    mi[512 + k] = s;
    sS[k] = s * s;
    float g = ws[OFF_M + p * DD + p];
    ws[OFF_SHAD + k]  = g - 1.0f;
    ws[OFF_SSNAP + k] = g - 1.0f;                     // stage-0 snapshot
    for (int i = k; i < 512; i += 128) pm[i] = -1;
    __syncthreads();
    pm[p] = k;
    if (k == 0) {
        int acc = 0;
        for (int i = 0; i < 128; ++i) { mi[640 + i] = acc; acc += sS[i]; }
        misc[0] = pos[127];
    }
}

// ---------------------------------------------------------------- stage-0 fork snapshots (raw G regions)
__global__ void k_snap0(float* __restrict__ ws) {
    const int* mi = (const int*)ws + OFF_MI;
    int r0 = blockIdx.x * 32, c0 = blockIdx.y * 32, tid = threadIdx.x;
    int cl = tid & 31, rl0 = tid >> 5;
    for (int k = 0; k < 128; ++k) {
        if (mi[384 + k] != 0) continue;
        int x = mi[256 + k];
        if (r0 >= x || c0 >= x) continue;
        int s = mi[512 + k];
        float* buf = ws + OFF_FORK + mi[640 + k];
        for (int e = 0; e < 4; ++e) {
            int gr = r0 + rl0 + e * 8, gc = c0 + cl;
            if (gr < x && gc < x) buf[gr * s + gc] = ws[OFF_M + gr * DD + gc];
        }
    }
}

// ---------------------------------------------------------------- chain panel: wave0 block LU + f4 right-looking solves
__global__ void __launch_bounds__(1024) k_panel(float* __restrict__ ws, int t) {
    const int* misc = (const int*)ws + OFF_MISC;
    int j0 = t * 32;
    if (j0 > misc[0]) return;
    const int* pm = (const int*)ws + OFF_POSMAP;
    __shared__ float dblk[32][36], dblkT[32][36];
    __shared__ float pvs[32];
    __shared__ float shadL[128];
    __shared__ int   chfL[32];
    int tid = threadIdx.x;
    int jn = j0 + 32, w = DD - jn;
    if (tid < 128) { float sv = ws[OFF_SHAD + tid]; shadL[tid] = sv; ws[OFF_SSNAP + t * 128 + tid] = sv; }
    if (tid < 32) chfL[tid] = pm[j0 + tid];
    __syncthreads();
    if (tid < 32) {
        float a[32];
#pragma unroll
        for (int c = 0; c < 32; ++c) a[c] = ws[OFF_M + (size_t)(j0 + tid) * DD + j0 + c];
        int cf = chfL[tid];
        float sh = (cf >= 0) ? shadL[cf] : 0.0f;
        unsigned long long bm = __ballot(cf >= 0);
        sh = w0_block_lu<true>(a, sh, bm, 32, 31, pvs, dblk, dblkT, ws + OFF_CPIV, j0, -1, tid);
        if (cf >= 0) ws[OFF_SHAD + cf] = sh;
    }
    __syncthreads();
    for (int task = tid; task < 2 * w; task += 1024) {
        if (task < w) {                               // L21 row r = jn+task
            int r = jn + task;
            const float* src = ws + OFF_M + (size_t)r * DD + j0;
            float a[32];
#pragma unroll
            for (int c = 0; c < 32; ++c) a[c] = src[c];
            solve_L21_row(a, dblk, pvs);
            float* dst = ws + OFF_LP + (size_t)r * 32;
#pragma unroll
            for (int c = 0; c < 32; ++c) dst[c] = a[c];
        } else {                                      // U12 col
            int col = jn + (task - w);
            float v[32];
#pragma unroll
            for (int j = 0; j < 32; ++j) v[j] = ws[OFF_M + (size_t)(j0 + j) * DD + col];
            solve_U12_col(v, dblkT);
#pragma unroll
            for (int j = 0; j < 32; ++j) ws[OFF_UP + j * DD + col] = v[j];
        }
    }
}

// ------------------------------------- chain trailing GEMM (4-col reg tiles, f4 LDS) + shadows + snapshots
__global__ void k_trail(float* __restrict__ ws, int t) {
    const int* misc = (const int*)ws + OFF_MISC;
    int j0 = t * 32, jn = j0 + 32;
    if (jn > misc[0]) return;
    const int* mi = (const int*)ws + OFF_MI;
    const int* pm = (const int*)ws + OFF_POSMAP;
    int r0 = blockIdx.x * 32, c0 = blockIdx.y * 32, tid = threadIdx.x;
    if (r0 < jn || c0 < jn) return;
    __shared__ float Lt[32][36], Ut[32][36];
    int cl = tid & 31, rl0 = tid >> 5;
    for (int e = 0; e < 4; ++e) {
        int rl = rl0 + e * 8;
        Lt[rl][cl] = ws[OFF_LP + (r0 + rl) * 32 + cl];
        Ut[rl][cl] = ws[OFF_UP + rl * DD + c0 + cl];
    }
    __syncthreads();
    int r = tid >> 3, c4 = (tid & 7) << 2;
    int gr = r0 + r;
    float acc[4];
#pragma unroll
    for (int j = 0; j < 4; ++j) acc[j] = ws[OFF_M + (size_t)gr * DD + c0 + c4 + j];
#pragma unroll 8
    for (int jj = 0; jj < 32; ++jj) {
        float lv = Lt[r][jj];
        const float4 uv = *(const float4*)&Ut[jj][c4];
        acc[0] = fmaf(-lv, uv.x, acc[0]); acc[1] = fmaf(-lv, uv.y, acc[1]);
        acc[2] = fmaf(-lv, uv.z, acc[2]); acc[3] = fmaf(-lv, uv.w, acc[3]);
    }
    // shadow: diagonal element (identical ordered fma chain on the shadow value)
    if (r0 == c0 && r >= c4 && r < c4 + 4) {
        int kk = pm[gr];
        if (kk >= 0) {
            float sv = ws[OFF_SHAD + kk];
#pragma unroll 8
            for (int jj = 0; jj < 32; ++jj) sv = fmaf(-Lt[r][jj], Ut[jj][r], sv);
            ws[OFF_SHAD + kk] = sv;
        }
    }
#pragma unroll
    for (int j = 0; j < 4; ++j) ws[OFF_M + (size_t)gr * DD + c0 + c4 + j] = acc[j];
    // snapshot regions for forks starting at stage t+1 (values from registers)
    for (int k = 0; k < 128; ++k) {
        if (mi[384 + k] != jn) continue;
        int x = mi[256 + k];
        if (r0 >= x || c0 >= x || gr >= x) continue;
        int s = mi[512 + k];
        float* buf = ws + OFF_FORK + mi[640 + k];
#pragma unroll
        for (int j = 0; j < 4; ++j) {
            int gc = c0 + c4 + j;
            if (gc < x) buf[(size_t)(gr - jn) * s + (gc - jn)] = acc[j];
        }
    }
}

// ---------------------------------------------------------------- per-row fork: blocked LU, f4 LDS, 8x8 GEMM tiles
__global__ void __launch_bounds__(1024) k_fork(float* __restrict__ ws) {
    const int* mi = (const int*)ws + OFF_MI;
    const int* pm = (const int*)ws + OFF_POSMAP;
    int k = blockIdx.x;
    int p = mi[k], x = mi[256 + k], j0 = mi[384 + k], s = mi[512 + k];
    if (p >= x - 1) return;
    float* buf = ws + OFF_FORK + mi[640 + k];
    float* fpv = ws + OFF_FPIV + k * DD;
    int tstage = j0 >> 5;
    __shared__ float dblk[32][36], dblkT[32][36];
    __shared__ float pvs[32];
    __shared__ float fpanT[32][360];                  // transposed L21: fpanT[jj][r], 16B-aligned rows
    __shared__ float fstrip[32][360];                 // U12 strip: fstrip[jj][c]
    int tid = threadIdx.x;
    int xl = s - 1;                                   // local index of last needed column (record-only)
    for (int pf0 = 0;; pf0 += 32) {
        int rem = xl - pf0;
        // ---- Phase S: wave0 lanes 0-31: diag-block LU (no barriers inside)
        if (tid < 32) {
            float a[32];
#pragma unroll
            for (int c = 0; c < 32; ++c) {
                int rr = pf0 + tid, cc = pf0 + c;
                a[c] = (rr <= xl && cc <= xl) ? buf[(size_t)rr * s + cc] : 0.0f;
            }
            float sh = 0.0f;
            unsigned long long bm = 0ull;
            if (pf0 == 0) {
                int g = j0 + tid;
                int kk = pm[g];
                bool ch = (kk >= 0 && g < p);         // chosen cols before p use shadow pivots
                if (ch) sh = ws[OFF_SSNAP + tstage * 128 + kk];
                bm = __ballot(ch);
            }
            int elim = rem < 32 ? rem : 32;
            int recl = rem < 31 ? rem : 31;
            w0_block_lu<false>(a, sh, bm, elim, recl, pvs, dblk, dblkT, fpv, j0 + pf0, p, tid);
        }
        if (rem < 32) break;                          // uniform: final (partial) block handled, done
        __syncthreads();
        int tw = s - pf0 - 32;                        // square trailing size (<=353)
        // ---- Phase P: L21 rows (tid<tw) and U12 cols (tid-512<tw), independent, no sync
        if (tid < tw) {
            int r = pf0 + 32 + tid;
            const float* src = buf + (size_t)r * s + pf0;
            float a[32];
#pragma unroll
            for (int c = 0; c < 32; ++c) a[c] = src[c];
            solve_L21_row(a, dblk, pvs);
#pragma unroll
            for (int c = 0; c < 32; ++c) fpanT[c][tid] = a[c];
        } else if (tid >= 512 && tid < 512 + tw) {
            int u = tid - 512;
            int col = pf0 + 32 + u;
            float v[32];
#pragma unroll
            for (int j = 0; j < 32; ++j) v[j] = buf[(size_t)(pf0 + j) * s + col];
            solve_U12_col(v, dblkT);
#pragma unroll
            for (int j = 0; j < 32; ++j) fstrip[j][u] = v[j];
        }
        __syncthreads();
        // ---- Phase G: trailing GEMM  buf -= L21 * U12  (8x8 register tiles, f4 LDS reads)
        {
            int ntr = (tw + 7) >> 3;
            int nt2 = ntr * ntr;
            for (int tile = tid; tile < nt2; tile += 1024) {
                int ti = tile / ntr;
                int tr = ti << 3, tc = (tile - ti * ntr) << 3;
                int rb = pf0 + 32 + tr, cb = pf0 + 32 + tc;
                if (tr + 8 <= tw && tc + 8 <= tw) {   // interior fast path
                    float acc[8][8];
#pragma unroll
                    for (int i = 0; i < 8; ++i)
#pragma unroll
                        for (int j = 0; j < 8; ++j) acc[i][j] = buf[(size_t)(rb + i) * s + cb + j];
#pragma unroll 2
                    for (int jj = 0; jj < 32; ++jj) {
                        const float4 a0 = *(const float4*)&fpanT[jj][tr];
                        const float4 a1 = *(const float4*)&fpanT[jj][tr + 4];
                        const float4 b0 = *(const float4*)&fstrip[jj][tc];
                        const float4 b1 = *(const float4*)&fstrip[jj][tc + 4];
                        float av[8] = {a0.x, a0.y, a0.z, a0.w, a1.x, a1.y, a1.z, a1.w};
                        float bv[8] = {b0.x, b0.y, b0.z, b0.w, b1.x, b1.y, b1.z, b1.w};
#pragma unroll
                        for (int i = 0; i < 8; ++i)
#pragma unroll
                            for (int j = 0; j < 8; ++j)
                                acc[i][j] = fmaf(-av[i], bv[j], acc[i][j]);
                    }
#pragma unroll
                    for (int i = 0; i < 8; ++i)
#pragma unroll
                        for (int j = 0; j < 8; ++j) buf[(size_t)(rb + i) * s + cb + j] = acc[i][j];
                } else {                               // edge tile, guarded, static indices
                    int nr = tw - tr; nr = nr > 8 ? 8 : nr;
                    int nc = tw - tc; nc = nc > 8 ? 8 : nc;
                    float acc[8][8];
#pragma unroll
                    for (int i = 0; i < 8; ++i)
#pragma unroll
                        for (int j = 0; j < 8; ++j)
                            acc[i][j] = (i < nr && j < nc) ? buf[(size_t)(rb + i) * s + cb + j] : 0.0f;
                    for (int jj = 0; jj < 32; ++jj) {
                        float av[8], bv[8];
#pragma unroll
                        for (int i = 0; i < 8; ++i) av[i] = (i < nr) ? fpanT[jj][tr + i] : 0.0f;
#pragma unroll
                        for (int j = 0; j < 8; ++j) bv[j] = (j < nc) ? fstrip[jj][tc + j] : 0.0f;
#pragma unroll
                        for (int i = 0; i < 8; ++i)
#pragma unroll
                            for (int j = 0; j < 8; ++j)
                                acc[i][j] = fmaf(-av[i], bv[j], acc[i][j]);
                    }
#pragma unroll
                    for (int i = 0; i < 8; ++i)
#pragma unroll
                        for (int j = 0; j < 8; ++j)
                            if (i < nr && j < nc) buf[(size_t)(rb + i) * s + cb + j] = acc[i][j];
                }
            }
        }
        __syncthreads();
    }
}

// ---------------------------------------------------------------- probs rows: cumprod + threshold + log term
__global__ void k_epilogue(float* __restrict__ ws, float* __restrict__ out) {
    const int* mi = (const int*)ws + OFF_MI;
    int k = blockIdx.x, tid = threadIdx.x;
    __shared__ float row[512];
    __shared__ float pivs[512];
    int c = mi[128 + k], p = mi[k], x = mi[256 + k];
    for (int i = tid; i < 512; i += 256) {
        row[i] = 0.0f;
        pivs[i] = (i <= p) ? ws[OFF_CPIV + i] : ws[OFF_FPIV + k * DD + i];
    }
    __syncthreads();
    if (tid == 0) {                                   // exact serial fp order (matches reference cumprod)
        float cp = 1.0f;
        for (int i = c; i < x; ++i) {
            float pv = pivs[i];
            float pr = cp * (1.0f - pv);
            row[i] = (fabsf(pr) > 1e-15f) ? pr : 0.0f;
            cp = cp * pv;
        }
        ws[OFF_LOG + k] = logf(row[p]);
    }
    __syncthreads();
    for (int i = tid; i < 512; i += 256) out[k * DD + i] = row[i];
}

__global__ void k_logsum(float* __restrict__ ws, float* __restrict__ out) {
    __shared__ float lv[128];
    int tid = threadIdx.x;
    if (tid < 64) { lv[tid] = ws[OFF_LOG + tid]; lv[tid + 64] = ws[OFF_LOG + tid + 64]; }
    __syncthreads();
    if (tid == 0) {
        double sacc = 0.0;
        for (int i = 0; i < 128; ++i) sacc += (double)lv[i];
        out[65536] = (float)sacc;
    }
}

// ----------------------------------------------------------------
extern "C" void kernel_launch(void* const* d_in, const int* in_sizes, int n_in,
                              void* d_out, int out_size, void* d_ws, size_t ws_size,
                              hipStream_t stream) {
    const float* P   = (const float*)d_in[0];
    const int*   pos = (const int*)d_in[1];
    float* ws  = (float*)d_ws;
    float* out = (float*)d_out;

    k_build<<<dim3(16, 16), 256, 0, stream>>>(P, ws);
    k_meta<<<1, 128, 0, stream>>>(pos, ws);
    k_snap0<<<dim3(16, 16), 256, 0, stream>>>(ws);
    for (int t = 0; t < 16; ++t) {
        k_panel<<<1, 1024, 0, stream>>>(ws, t);
        if (t < 15) k_trail<<<dim3(16, 16), 256, 0, stream>>>(ws, t);
    }
    k_fork<<<128, 1024, 0, stream>>>(ws);
    k_epilogue<<<128, 256, 0, stream>>>(ws, out);
    k_logsum<<<1, 64, 0, stream>>>(ws, out);
}

// Round 6
// 1883.721 us; speedup vs baseline: 1.5907x; 1.1338x over previous
//
#include <hip/hip_runtime.h>
#include <math.h>

// Problem constants
#define DD 512
#define NN 128
#define XBASE 385   // D - N + 1 ; xmax_k = XBASE + k

// Workspace layout (in 4-byte elements)
#define OFF_M      0            // 512*512 chain matrix
#define OFF_CPIV   294912       // 512     chain pivots (unshadowed diag at elimination time)
#define OFF_SHAD   295424       // 128     running shadow diagonals
#define OFF_SSNAP  295552       // 16*128  shadow snapshot at start of each stage
#define OFF_FPIV   297600       // 128*512 fork pivots
#define OFF_LOG    363136       // 128     per-row log(picked)
#define OFF_MI     363264       // 768 ints: [0..127]=p, [+128]=c, [+256]=x, [+384]=j0, [+512]=s, [+640]=pool off
#define OFF_POSMAP 364032       // 512 ints: site -> k or -1
#define OFF_MISC   364544       // ints: [0]=p127
#define OFF_FORK   364608       // fork snapshot pool (~25 MB)

// ---------------------------------------------------------------- wave 32x32 block LU (lanes 0-31, register rows, shfl broadcast)
// Identical per-element fp-op order as unblocked right-looking elimination restricted to the block.
// Writes dblk (row-major) and dblkT (transposed); rows padded to 36 floats (16B-aligned rows).
template<bool RECALL>
__device__ __forceinline__ float w0_block_lu(float (&a)[32], float sh,
    unsigned long long shmask, int elim, int recl, bool wrec,
    float* __restrict__ pvsL, float (*dblkL)[36], float (*dblkTL)[36],
    float* __restrict__ recp, int gbase, int gmin, int lane)
{
    bool mine = (shmask >> lane) & 1ull;
#pragma unroll
    for (int j = 0; j < 32; ++j) {
        if (j > recl) break;
        float d  = __shfl(a[j], j);
        float sj = __shfl(sh, j);
        if (lane == 0 && wrec) {
            int g = gbase + j;
            if (RECALL || g > gmin) recp[g] = d;
        }
        if (j >= elim) break;
        float pv = ((shmask >> j) & 1ull) ? sj : d;
        if (lane == 0) pvsL[j] = pv;
        bool below = lane > j;
        if (below) a[j] = a[j] / pv;
        float m = a[j];
#pragma unroll
        for (int c = j + 1; c < 32; ++c) {
            float bj = __shfl(a[c], j);
            if (below) {
                a[c] = fmaf(-m, bj, a[c]);
                if (mine && lane == c) sh = fmaf(-m, bj, sh);
            }
        }
    }
#pragma unroll
    for (int c = 0; c < 32; ++c) { dblkL[lane][c] = a[c]; dblkTL[c][lane] = a[c]; }
    return sh;
}

// -------- right-looking L21 row solve: bit-identical op sequence to left-looking
__device__ __forceinline__ void solve_L21_row(float (&a)[32], const float (*dblk)[36],
                                              const float* __restrict__ pvs) {
#pragma unroll
    for (int c = 0; c < 32; ++c) {
        a[c] = a[c] / pvs[c];
        float m = a[c];
        int j = c + 1;
#pragma unroll
        for (; (j & 3) && j < 32; ++j) a[j] = fmaf(-m, dblk[c][j], a[j]);
#pragma unroll
        for (; j + 3 < 32; j += 4) {
            const float4 u = *(const float4*)&dblk[c][j];
            a[j+0] = fmaf(-m, u.x, a[j+0]); a[j+1] = fmaf(-m, u.y, a[j+1]);
            a[j+2] = fmaf(-m, u.z, a[j+2]); a[j+3] = fmaf(-m, u.w, a[j+3]);
        }
    }
}

// -------- right-looking U12 col solve (no divide); bit-identical order.
__device__ __forceinline__ void solve_U12_col(float (&v)[32], const float (*dblkT)[36]) {
#pragma unroll
    for (int c = 0; c < 31; ++c) {
        float vc = v[c];
        int j = c + 1;
#pragma unroll
        for (; (j & 3) && j < 32; ++j) v[j] = fmaf(-dblkT[c][j], vc, v[j]);
#pragma unroll
        for (; j + 3 < 32; j += 4) {
            const float4 u = *(const float4*)&dblkT[c][j];
            v[j+0] = fmaf(-u.x, vc, v[j+0]); v[j+1] = fmaf(-u.y, vc, v[j+1]);
            v[j+2] = fmaf(-u.z, vc, v[j+2]); v[j+3] = fmaf(-u.w, vc, v[j+3]);
        }
    }
}

// ---------------------------------------------------------------- G = I - P P^T
__global__ void k_build(const float* __restrict__ P, float* __restrict__ ws) {
    __shared__ float Pr[32][129];
    __shared__ float Pc[32][129];
    int r0 = blockIdx.x * 32, c0 = blockIdx.y * 32, tid = threadIdx.x;
    for (int idx = tid; idx < 32 * 128; idx += 256) {
        int r = idx >> 7, t = idx & 127;
        Pr[r][t] = P[(r0 + r) * NN + t];
        Pc[r][t] = P[(c0 + r) * NN + t];
    }
    __syncthreads();
    int cl = tid & 31, rl0 = tid >> 5;
    for (int e = 0; e < 4; ++e) {
        int rl = rl0 + e * 8;
        float acc = 0.0f;
#pragma unroll 8
        for (int t = 0; t < 128; ++t) acc = fmaf(Pr[rl][t], Pc[cl][t], acc);
        int gr = r0 + rl, gc = c0 + cl;
        ws[OFF_M + gr * DD + gc] = ((gr == gc) ? 1.0f : 0.0f) - acc;
    }
}

// ---------------------------------------------------------------- per-k metadata + shadow init
__global__ void k_meta(const int* __restrict__ pos, float* __restrict__ ws) {
    int* mi   = (int*)ws + OFF_MI;
    int* pm   = (int*)ws + OFF_POSMAP;
    int* misc = (int*)ws + OFF_MISC;
    __shared__ int sS[128];
    int k = threadIdx.x;           // blockDim.x == 128
    int p = pos[k];
    mi[k] = p;
    mi[128 + k] = (k == 0) ? 0 : (pos[k - 1] + 1);   // c_k = xmin_k
    int x = XBASE + k;                                // xmax_k
    mi[256 + k] = x;
    int j0 = (p >> 5) << 5;                           // fork start column (stage boundary)
    mi[384 + k] = j0;
    int s = x - j0;                                   // fork submatrix side (<=385)
    mi[512 + k] = s;
    sS[k] = s * s;
    float g = ws[OFF_M + p * DD + p];
    ws[OFF_SHAD + k]  = g - 1.0f;
    ws[OFF_SSNAP + k] = g - 1.0f;                     // stage-0 snapshot
    for (int i = k; i < 512; i += 128) pm[i] = -1;
    __syncthreads();
    pm[p] = k;
    if (k == 0) {
        int acc = 0;
        for (int i = 0; i < 128; ++i) { mi[640 + i] = acc; acc += sS[i]; }
        misc[0] = pos[127];
    }
}

// ---------------------------------------------------------------- stage-0 fork snapshots (raw G regions)
__global__ void k_snap0(float* __restrict__ ws) {
    const int* mi = (const int*)ws + OFF_MI;
    int r0 = blockIdx.x * 32, c0 = blockIdx.y * 32, tid = threadIdx.x;
    int cl = tid & 31, rl0 = tid >> 5;
    for (int k = 0; k < 128; ++k) {
        if (mi[384 + k] != 0) continue;
        int x = mi[256 + k];
        if (r0 >= x || c0 >= x) continue;
        int s = mi[512 + k];
        float* buf = ws + OFF_FORK + mi[640 + k];
        for (int e = 0; e < 4; ++e) {
            int gr = r0 + rl0 + e * 8, gc = c0 + cl;
            if (gr < x && gc < x) buf[gr * s + gc] = ws[OFF_M + gr * DD + gc];
        }
    }
}

// ------------------------------------- merged chain stage: per-block w0 LU + local solves + GEMM + shadows + snapshots
__global__ void __launch_bounds__(256) k_stage(float* __restrict__ ws, int t) {
    const int* misc = (const int*)ws + OFF_MISC;
    int j0 = t * 32, jn = j0 + 32;
    if (j0 > misc[0]) return;                         // chain only needed through p127
    const int* mi = (const int*)ws + OFF_MI;
    const int* pm = (const int*)ws + OFF_POSMAP;
    int bx = blockIdx.x, by = blockIdx.y;
    bool root = (bx == 0 && by == 0);
    bool trail = (jn <= misc[0]);                     // trailing update needed at all?
    if (!trail && !root) return;
    __shared__ float dblk[32][36], dblkT[32][36];
    __shared__ float pvs[32];
    __shared__ float Lt[32][36], Ut[32][36];
    int tid = threadIdx.x;
    // ---- redundant per-block 32x32 panel LU (bit-identical across blocks); root writes CPIV
    if (tid < 32) {
        float a[32];
#pragma unroll
        for (int c = 0; c < 32; ++c) a[c] = ws[OFF_M + (size_t)(j0 + tid) * DD + j0 + c];
        int cf = pm[j0 + tid];
        float sh = (cf >= 0) ? ws[OFF_SSNAP + t * 128 + cf] : 0.0f;   // shadow at start of stage t
        unsigned long long bm = __ballot(cf >= 0);
        w0_block_lu<true>(a, sh, bm, 32, 31, root, pvs, dblk, dblkT, ws + OFF_CPIV, j0, -1, tid);
    }
    if (!trail) return;
    int r0 = jn + bx * 32, c0 = jn + by * 32;
    __syncthreads();
    // ---- local L21 rows (wave0 lanes 0-31) and U12 cols (wave1 lanes 0-31), parallel
    if (tid < 32) {
        float a[32];
#pragma unroll
        for (int c = 0; c < 32; ++c) a[c] = ws[OFF_M + (size_t)(r0 + tid) * DD + j0 + c];
        solve_L21_row(a, dblk, pvs);
#pragma unroll
        for (int c = 0; c < 32; ++c) Lt[tid][c] = a[c];
    } else if (tid >= 64 && tid < 96) {
        int u = tid - 64;
        float v[32];
#pragma unroll
        for (int j = 0; j < 32; ++j) v[j] = ws[OFF_M + (size_t)(j0 + j) * DD + c0 + u];
        solve_U12_col(v, dblkT);
#pragma unroll
        for (int j = 0; j < 32; ++j) Ut[j][u] = v[j];
    }
    __syncthreads();
    // ---- trailing GEMM tile (1 row x 4 cols per thread)
    int r = tid >> 3, c4 = (tid & 7) << 2;
    int gr = r0 + r;
    float acc[4];
#pragma unroll
    for (int j = 0; j < 4; ++j) acc[j] = ws[OFF_M + (size_t)gr * DD + c0 + c4 + j];
#pragma unroll 8
    for (int jj = 0; jj < 32; ++jj) {
        float lv = Lt[r][jj];
        const float4 uv = *(const float4*)&Ut[jj][c4];
        acc[0] = fmaf(-lv, uv.x, acc[0]); acc[1] = fmaf(-lv, uv.y, acc[1]);
        acc[2] = fmaf(-lv, uv.z, acc[2]); acc[3] = fmaf(-lv, uv.w, acc[3]);
    }
    // shadow of chosen diag entries (identical ordered fma chain); root also snapshots for panel t+1
    if (bx == by && r >= c4 && r < c4 + 4) {
        int kk = pm[gr];
        if (kk >= 0) {
            float sv = ws[OFF_SHAD + kk];
#pragma unroll 8
            for (int jj = 0; jj < 32; ++jj) sv = fmaf(-Lt[r][jj], Ut[jj][r], sv);
            ws[OFF_SHAD + kk] = sv;
            if (root) ws[OFF_SSNAP + (t + 1) * 128 + kk] = sv;   // value at start of stage t+1
        }
    }
#pragma unroll
    for (int j = 0; j < 4; ++j) ws[OFF_M + (size_t)gr * DD + c0 + c4 + j] = acc[j];
    // snapshot regions for forks starting at stage t+1 (values from registers)
    for (int k = 0; k < 128; ++k) {
        if (mi[384 + k] != jn) continue;
        int x = mi[256 + k];
        if (r0 >= x || c0 >= x || gr >= x) continue;
        int s = mi[512 + k];
        float* buf = ws + OFF_FORK + mi[640 + k];
#pragma unroll
        for (int j = 0; j < 4; ++j) {
            int gc = c0 + c4 + j;
            if (gc < x) buf[(size_t)(gr - jn) * s + (gc - jn)] = acc[j];
        }
    }
}

// ---------------------------------------------------------------- per-row fork: blocked LU, wave-tiled 8x8 GEMM
__global__ void __launch_bounds__(512, 2) k_fork(float* __restrict__ ws) {
    const int* mi = (const int*)ws + OFF_MI;
    const int* pm = (const int*)ws + OFF_POSMAP;
    int k = blockIdx.x;
    int p = mi[k], x = mi[256 + k], j0 = mi[384 + k], s = mi[512 + k];
    if (p >= x - 1) return;
    float* buf = ws + OFF_FORK + mi[640 + k];
    float* fpv = ws + OFF_FPIV + k * DD;
    int tstage = j0 >> 5;
    __shared__ float dblk[32][36], dblkT[32][36];
    __shared__ float pvs[32];
    __shared__ float fpanT[32][360];                  // transposed L21: fpanT[jj][r]
    __shared__ float fstrip[32][360];                 // U12 strip: fstrip[jj][c]
    int tid = threadIdx.x;
    int lane = tid & 63;
    int li = lane >> 3, lj = lane & 7;                // 8x8 lane grid within wave
    int wid = tid >> 6;                               // wave id 0..7
    int xl = s - 1;                                   // local index of last needed column (record-only)
    for (int pf0 = 0;; pf0 += 32) {
        int rem = xl - pf0;
        // ---- Phase S: lanes 0-31 of wave0: diag-block LU (no barriers inside)
        if (tid < 32) {
            float a[32];
#pragma unroll
            for (int c = 0; c < 32; ++c) {
                int rr = pf0 + tid, cc = pf0 + c;
                a[c] = (rr <= xl && cc <= xl) ? buf[(size_t)rr * s + cc] : 0.0f;
            }
            float sh = 0.0f;
            unsigned long long bm = 0ull;
            if (pf0 == 0) {
                int g = j0 + tid;
                int kk = pm[g];
                bool ch = (kk >= 0 && g < p);         // chosen cols before p use shadow pivots
                if (ch) sh = ws[OFF_SSNAP + tstage * 128 + kk];
                bm = __ballot(ch);
            }
            int elim = rem < 32 ? rem : 32;
            int recl = rem < 31 ? rem : 31;
            w0_block_lu<false>(a, sh, bm, elim, recl, true, pvs, dblk, dblkT, fpv, j0 + pf0, p, tid);
        }
        if (rem < 32) break;                          // uniform: final (partial) block handled
        __syncthreads();
        int tw = s - pf0 - 32;                        // square trailing size (<=353)
        // ---- Phase P: L21 rows and U12 cols (2*tw tasks over 512 threads)
        for (int task = tid; task < 2 * tw; task += 512) {
            if (task < tw) {
                int r = pf0 + 32 + task;
                const float* src = buf + (size_t)r * s + pf0;
                float a[32];
#pragma unroll
                for (int c = 0; c < 32; ++c) a[c] = src[c];
                solve_L21_row(a, dblk, pvs);
#pragma unroll
                for (int c = 0; c < 32; ++c) fpanT[c][task] = a[c];
            } else {
                int u = task - tw;
                int col = pf0 + 32 + u;
                float v[32];
#pragma unroll
                for (int j = 0; j < 32; ++j) v[j] = buf[(size_t)(pf0 + j) * s + col];
                solve_U12_col(v, dblkT);
#pragma unroll
                for (int j = 0; j < 32; ++j) fstrip[j][u] = v[j];
            }
        }
        __syncthreads();
        // ---- Phase G: trailing GEMM, wave-tiled: each wave covers a 64x64 macro, lane (li,lj) an 8x8 tile.
        //      LDS reads: 8 distinct f4 addresses broadcast across the other lane dim (2-way aliasing = free).
        {
            int base = pf0 + 32;
            int nmacro = (tw + 63) >> 6;
            int nmac2 = nmacro * nmacro;
            for (int m = wid; m < nmac2; m += 8) {
                int wr = m / nmacro, wc = m - wr * nmacro;
                int tr = ((wr << 3) + li) << 3;
                int tc = ((wc << 3) + lj) << 3;
                int rb = base + tr, cb = base + tc;
                bool interior = (((wr + 1) << 6) <= tw) && (((wc + 1) << 6) <= tw);
                if (interior) {
                    float acc[8][8];
#pragma unroll
                    for (int i = 0; i < 8; ++i)
#pragma unroll
                        for (int j = 0; j < 8; ++j) acc[i][j] = buf[(size_t)(rb + i) * s + cb + j];
#pragma unroll 2
                    for (int jj = 0; jj < 32; ++jj) {
                        const float4 a0 = *(const float4*)&fpanT[jj][tr];
                        const float4 a1 = *(const float4*)&fpanT[jj][tr + 4];
                        const float4 b0 = *(const float4*)&fstrip[jj][tc];
                        const float4 b1 = *(const float4*)&fstrip[jj][tc + 4];
                        float av[8] = {a0.x, a0.y, a0.z, a0.w, a1.x, a1.y, a1.z, a1.w};
                        float bv[8] = {b0.x, b0.y, b0.z, b0.w, b1.x, b1.y, b1.z, b1.w};
#pragma unroll
                        for (int i = 0; i < 8; ++i)
#pragma unroll
                            for (int j = 0; j < 8; ++j)
                                acc[i][j] = fmaf(-av[i], bv[j], acc[i][j]);
                    }
#pragma unroll
                    for (int i = 0; i < 8; ++i)
#pragma unroll
                        for (int j = 0; j < 8; ++j) buf[(size_t)(rb + i) * s + cb + j] = acc[i][j];
                } else {
                    int nr = tw - tr; nr = nr < 0 ? 0 : (nr > 8 ? 8 : nr);
                    int nc = tw - tc; nc = nc < 0 ? 0 : (nc > 8 ? 8 : nc);
                    if (nr > 0 && nc > 0) {
                        float acc[8][8];
#pragma unroll
                        for (int i = 0; i < 8; ++i)
#pragma unroll
                            for (int j = 0; j < 8; ++j)
                                acc[i][j] = (i < nr && j < nc) ? buf[(size_t)(rb + i) * s + cb + j] : 0.0f;
                        for (int jj = 0; jj < 32; ++jj) {
                            float av[8], bv[8];
#pragma unroll
                            for (int i = 0; i < 8; ++i) av[i] = (i < nr) ? fpanT[jj][tr + i] : 0.0f;
#pragma unroll
                            for (int j = 0; j < 8; ++j) bv[j] = (j < nc) ? fstrip[jj][tc + j] : 0.0f;
#pragma unroll
                            for (int i = 0; i < 8; ++i)
#pragma unroll
                                for (int j = 0; j < 8; ++j)
                                    acc[i][j] = fmaf(-av[i], bv[j], acc[i][j]);
                        }
#pragma unroll
                        for (int i = 0; i < 8; ++i)
#pragma unroll
                            for (int j = 0; j < 8; ++j)
                                if (i < nr && j < nc) buf[(size_t)(rb + i) * s + cb + j] = acc[i][j];
                    }
                }
            }
        }
        __syncthreads();
    }
}

// ---------------------------------------------------------------- probs rows: cumprod + threshold + log term
__global__ void k_epilogue(float* __restrict__ ws, float* __restrict__ out) {
    const int* mi = (const int*)ws + OFF_MI;
    int k = blockIdx.x, tid = threadIdx.x;
    __shared__ float row[512];
    __shared__ float pivs[512];
    int c = mi[128 + k], p = mi[k], x = mi[256 + k];
    for (int i = tid; i < 512; i += 256) {
        row[i] = 0.0f;
        pivs[i] = (i <= p) ? ws[OFF_CPIV + i] : ws[OFF_FPIV + k * DD + i];
    }
    __syncthreads();
    if (tid == 0) {                                   // exact serial fp order (matches reference cumprod)
        float cp = 1.0f;
        for (int i = c; i < x; ++i) {
            float pv = pivs[i];
            float pr = cp * (1.0f - pv);
            row[i] = (fabsf(pr) > 1e-15f) ? pr : 0.0f;
            cp = cp * pv;
        }
        ws[OFF_LOG + k] = logf(row[p]);
    }
    __syncthreads();
    for (int i = tid; i < 512; i += 256) out[k * DD + i] = row[i];
}

__global__ void k_logsum(float* __restrict__ ws, float* __restrict__ out) {
    __shared__ float lv[128];
    int tid = threadIdx.x;
    if (tid < 64) { lv[tid] = ws[OFF_LOG + tid]; lv[tid + 64] = ws[OFF_LOG + tid + 64]; }
    __syncthreads();
    if (tid == 0) {
        double sacc = 0.0;
        for (int i = 0; i < 128; ++i) sacc += (double)lv[i];
        out[65536] = (float)sacc;
    }
}

// ----------------------------------------------------------------
extern "C" void kernel_launch(void* const* d_in, const int* in_sizes, int n_in,
                              void* d_out, int out_size, void* d_ws, size_t ws_size,
                              hipStream_t stream) {
    const float* P   = (const float*)d_in[0];
    const int*   pos = (const int*)d_in[1];
    float* ws  = (float*)d_ws;
    float* out = (float*)d_out;

    k_build<<<dim3(16, 16), 256, 0, stream>>>(P, ws);
    k_meta<<<1, 128, 0, stream>>>(pos, ws);
    k_snap0<<<dim3(16, 16), 256, 0, stream>>>(ws);
    for (int t = 0; t < 16; ++t) {
        int gt = 15 - t; if (gt < 1) gt = 1;
        k_stage<<<dim3(gt, gt), 256, 0, stream>>>(ws, t);
    }
    k_fork<<<128, 512, 0, stream>>>(ws);
    k_epilogue<<<128, 256, 0, stream>>>(ws, out);
    k_logsum<<<1, 64, 0, stream>>>(ws, out);
}